// Round 11
// baseline (193.453 us; speedup 1.0000x reference)
//
#include <hip/hip_runtime.h>

#define N_NODES 100000
#define N_EDGES 3200000
#define IN_F    256
#define OUT_F   256
#define CLAMP_V 10.0f

typedef __attribute__((ext_vector_type(8))) short bf16x8;
typedef __attribute__((ext_vector_type(4))) float f32x4;

__device__ __forceinline__ float clampf(float v) {
    return fminf(fmaxf(v, -CLAMP_V), CLAMP_V);
}
// RNE float -> bf16 (inputs clamped/finite)
__device__ __forceinline__ unsigned f2bf(float f) {
    unsigned u = __float_as_uint(f);
    u += 0x7fffu + ((u >> 16) & 1u);
    return u >> 16;
}
// packed 2x f32 -> 2x bf16 in one u32
__device__ __forceinline__ unsigned cvt_pk_bf16(float lo, float hi) {
    unsigned r;
    asm("v_cvt_pk_bf16_f32 %0, %1, %2" : "=v"(r) : "v"(lo), "v"(hi));
    return r;
}
__device__ __forceinline__ float bflo(unsigned w) { return __uint_as_float(w << 16); }
__device__ __forceinline__ float bfhi(unsigned w) { return __uint_as_float(w & 0xffff0000u); }

// ---------------------------------------------------------------------------
// Kernel 0 (merged): blocks 0..255 convert W -> bf16 k-major
//   element (k,n) at ushort idx (k>>3)*2048 + n*8 + (k&7);
// blocks 256.. build CSR row_ptr from sorted adj_rows (binary search).
// ---------------------------------------------------------------------------
__global__ __launch_bounds__(256) void prep(
    const float* __restrict__ w, unsigned short* __restrict__ wt,
    const int* __restrict__ rows, int* __restrict__ row_ptr) {
    const int bid = blockIdx.x;
    if (bid < 256) {
        int i = bid * 256 + threadIdx.x;   // 65536
        int k = i & 255, n = i >> 8;
        float v = w[(size_t)k * OUT_F + n];
        int dst = ((k >> 3) << 11) + (n << 3) + (k & 7);
        wt[dst] = (unsigned short)f2bf(v);
    } else {
        int r = (bid - 256) * 256 + threadIdx.x;
        if (r > N_NODES) return;
        int lo = 0, hi = N_EDGES;
        while (lo < hi) {
            int mid = (lo + hi) >> 1;
            if (rows[mid] < r) lo = mid + 1; else hi = mid;
        }
        row_ptr[r] = lo;
    }
}

// ---------------------------------------------------------------------------
// Kernel 1: fused GEMM + int8 quantization, LDS-staged x streaming.
// (unchanged from R10 — delivered its prediction)
// ---------------------------------------------------------------------------
__global__ __launch_bounds__(256) void gemm_mfma(
    const float* __restrict__ x, const unsigned short* __restrict__ wt,
    unsigned* __restrict__ sup8, float* __restrict__ scales) {
    __shared__ char lds[32768];     // 2 x 16 KB staging; reused by epilogue

    const int t    = threadIdx.x;
    const int lane = t & 63;
    const int wc   = t >> 6;        // wave id = col slice 0..3
    const int l15  = lane & 15;
    const int l4   = lane >> 4;     // 0..3
    const int blockRow = blockIdx.x * 64;

    const int srow = t >> 2;        // 0..63
    const int sqt  = t & 3;         // 64B quarter of the 256B row-step slice
    int sgrow = blockRow + srow; if (sgrow >= N_NODES) sgrow = N_NODES - 1;
    const float* sbase = x + (size_t)sgrow * IN_F + sqt * 16;
    int woff[4];
    #pragma unroll
    for (int j = 0; j < 4; ++j) {
        int chunk = sqt * 4 + j;
        woff[j] = srow * 256 + ((chunk ^ (srow & 15)) << 4);
    }

    f32x4 st[4];
    #pragma unroll
    for (int j = 0; j < 4; ++j)
        st[j] = *(const f32x4*)(sbase + j * 4);      // K-step 0

    f32x4 acc[4][4];
    #pragma unroll
    for (int m = 0; m < 4; ++m)
        #pragma unroll
        for (int n = 0; n < 4; ++n)
            acc[m][n] = (f32x4)0.f;

    #pragma unroll
    for (int s = 0; s < 4; ++s) {
        char* buf = lds + (s & 1) * 16384;
        #pragma unroll
        for (int j = 0; j < 4; ++j)
            *(f32x4*)(buf + woff[j]) = st[j];
        if (s < 3) {                                  // prefetch next K-step
            const float* nb = sbase + (s + 1) * 64;
            #pragma unroll
            for (int j = 0; j < 4; ++j)
                st[j] = *(const f32x4*)(nb + j * 4);
        }
        __syncthreads();

        #pragma unroll
        for (int kk = 0; kk < 2; ++kk) {
            bf16x8 a[4], b[4];
            #pragma unroll
            for (int m = 0; m < 4; ++m) {
                const int row = m * 16 + l15;
                const int c0 = (kk * 8 + l4 * 2 + 0) ^ l15;
                const int c1 = (kk * 8 + l4 * 2 + 1) ^ l15;
                f32x4 u0 = *(const f32x4*)(buf + row * 256 + (c0 << 4));
                f32x4 u1 = *(const f32x4*)(buf + row * 256 + (c1 << 4));
                union { unsigned u[4]; bf16x8 v; } pk;
                pk.u[0] = cvt_pk_bf16(clampf(u0[0]), clampf(u0[1]));
                pk.u[1] = cvt_pk_bf16(clampf(u0[2]), clampf(u0[3]));
                pk.u[2] = cvt_pk_bf16(clampf(u1[0]), clampf(u1[1]));
                pk.u[3] = cvt_pk_bf16(clampf(u1[2]), clampf(u1[3]));
                a[m] = pk.v;
            }
            const int kg = s * 8 + kk * 4 + l4;       // global k>>3
            #pragma unroll
            for (int n = 0; n < 4; ++n)
                b[n] = *(const bf16x8*)(wt + (kg << 11) + ((wc * 64 + n * 16 + l15) << 3));
            #pragma unroll
            for (int m = 0; m < 4; ++m)
                #pragma unroll
                for (int n = 0; n < 4; ++n)
                    acc[m][n] = __builtin_amdgcn_mfma_f32_16x16x32_bf16(
                        a[m], b[n], acc[m][n], 0, 0, 0);
        }
    }
    __syncthreads();

    // ---- epilogue A: acc -> LDS bf16 (chunk-swizzled), 64 x 512 B ----
    {
        char* sl = lds;
        #pragma unroll
        for (int m = 0; m < 4; ++m) {
            #pragma unroll
            for (int n = 0; n < 4; ++n) {
                int col2 = (wc * 64 + n * 16 + l15) * 2;
                #pragma unroll
                for (int r = 0; r < 4; ++r) {
                    int row = m * 16 + l4 * 4 + r;
                    int off = row * 512 + (col2 ^ (((row >> 2) & 3) << 4));
                    *(unsigned short*)(sl + off) = (unsigned short)f2bf(clampf(acc[m][n][r]));
                }
            }
        }
    }
    __syncthreads();

    // ---- epilogue B: rowmax + quantize + int8 store ----
    {
        const uint4* sl4 = (const uint4*)lds;
        const int row = t >> 2;         // 0..63
        const int qt  = t & 3;          // quarter of the row (64 feats)
        const int swz = (row >> 2) & 3;

        uint4 c[8];
        float mx = 0.f;
        #pragma unroll
        for (int j = 0; j < 8; ++j) {
            c[j] = sl4[row * 32 + ((qt * 8 + j) ^ swz)];
            const unsigned* cu = (const unsigned*)&c[j];
            #pragma unroll
            for (int q = 0; q < 4; ++q)
                mx = fmaxf(mx, fmaxf(fabsf(bflo(cu[q])), fabsf(bfhi(cu[q]))));
        }
        mx = fmaxf(mx, __shfl_xor(mx, 1));
        mx = fmaxf(mx, __shfl_xor(mx, 2));   // rowmax in all 4 quarter-threads

        const float inv = 127.f / fmaxf(mx, 1e-30f);
        const int grow = blockRow + row;
        if (grow < N_NODES) {
            unsigned p[16];
            #pragma unroll
            for (int j = 0; j < 8; ++j) {
                const unsigned* cu = (const unsigned*)&c[j];
                #pragma unroll
                for (int q = 0; q < 2; ++q) {
                    unsigned b0 = (unsigned)(int)rintf(bflo(cu[q*2+0]) * inv) + 128u;
                    unsigned b1 = (unsigned)(int)rintf(bfhi(cu[q*2+0]) * inv) + 128u;
                    unsigned b2 = (unsigned)(int)rintf(bflo(cu[q*2+1]) * inv) + 128u;
                    unsigned b3 = (unsigned)(int)rintf(bfhi(cu[q*2+1]) * inv) + 128u;
                    p[j*2+q] = b0 | (b1 << 8) | (b2 << 16) | (b3 << 24);
                }
            }
            uint4* dst = (uint4*)(sup8 + (size_t)grow * 64 + qt * 16);
            #pragma unroll
            for (int j = 0; j < 4; ++j)
                dst[j] = *(const uint4*)&p[j * 4];
            if (qt == 0) scales[grow] = mx * (1.f / 127.f);
        }
    }
}

// ---------------------------------------------------------------------------
// Kernel 2: out[r] = clip(relu(clip(sum val*support[c]) + bias)).
// QUARTER-WAVE layout: 4 quarters x 16 lanes; each quarter owns one edge,
// lane holds 16 bytes (uint4) of the col row -> 1 KB per VMEM instr, 16
// edges in flight in the main loop. acc[16]+S reduced across quarters via
// shfl_xor(16,32) at the end. Dequant folded, -128*S correction.
// ---------------------------------------------------------------------------
#define FMAQ16(g, vs)                                                     \
    S += (vs);                                                            \
    acc[ 0] += (vs) * (float)((g).x & 0xffu);                             \
    acc[ 1] += (vs) * (float)(((g).x >> 8) & 0xffu);                      \
    acc[ 2] += (vs) * (float)(((g).x >> 16) & 0xffu);                     \
    acc[ 3] += (vs) * (float)((g).x >> 24);                               \
    acc[ 4] += (vs) * (float)((g).y & 0xffu);                             \
    acc[ 5] += (vs) * (float)(((g).y >> 8) & 0xffu);                      \
    acc[ 6] += (vs) * (float)(((g).y >> 16) & 0xffu);                     \
    acc[ 7] += (vs) * (float)((g).y >> 24);                               \
    acc[ 8] += (vs) * (float)((g).z & 0xffu);                             \
    acc[ 9] += (vs) * (float)(((g).z >> 8) & 0xffu);                      \
    acc[10] += (vs) * (float)(((g).z >> 16) & 0xffu);                     \
    acc[11] += (vs) * (float)((g).z >> 24);                               \
    acc[12] += (vs) * (float)((g).w & 0xffu);                             \
    acc[13] += (vs) * (float)(((g).w >> 8) & 0xffu);                      \
    acc[14] += (vs) * (float)(((g).w >> 16) & 0xffu);                     \
    acc[15] += (vs) * (float)((g).w >> 24);

__global__ __launch_bounds__(256) void spmm_out(
    const unsigned* __restrict__ sup8, const float* __restrict__ scales,
    const int* __restrict__ row_ptr, const int* __restrict__ cols,
    const float* __restrict__ vals, const float* __restrict__ bias,
    float* __restrict__ out) {
    const int wid  = threadIdx.x >> 6;
    const int lane = threadIdx.x & 63;
    const int row  = blockIdx.x * 4 + wid;
    if (row >= N_NODES) return;

    const int e0 = row_ptr[row];
    const int e1 = row_ptr[row + 1];
    const int q  = lane >> 4;         // quarter id: edge slot within group
    const int fl = lane & 15;         // 16B feature-chunk within node row

    const uint4* sup16 = (const uint4*)sup8;   // 16 x 16B chunks per node
    float acc[16];
    #pragma unroll
    for (int j = 0; j < 16; ++j) acc[j] = 0.f;
    float S = 0.f;

    int e = e0;
    for (; e + 16 <= e1; e += 16) {           // 16 edges: 4 groups of 4
        int   i0 = e + q, i1 = i0 + 4, i2 = i0 + 8, i3 = i0 + 12;
        int   c0 = cols[i0], c1 = cols[i1], c2 = cols[i2], c3 = cols[i3];
        float v0 = vals[i0], v1 = vals[i1], v2 = vals[i2], v3 = vals[i3];
        float s0 = v0 * scales[c0], s1 = v1 * scales[c1];
        float s2 = v2 * scales[c2], s3 = v3 * scales[c3];
        uint4 g0 = sup16[(size_t)c0 * 16 + fl];
        uint4 g1 = sup16[(size_t)c1 * 16 + fl];
        uint4 g2 = sup16[(size_t)c2 * 16 + fl];
        uint4 g3 = sup16[(size_t)c3 * 16 + fl];
        FMAQ16(g0, s0); FMAQ16(g1, s1); FMAQ16(g2, s2); FMAQ16(g3, s3);
    }
    for (; e + 4 <= e1; e += 4) {             // 4-edge groups
        int   i0 = e + q;
        int   c0 = cols[i0];
        float v0 = vals[i0];
        float s0 = v0 * scales[c0];
        uint4 g0 = sup16[(size_t)c0 * 16 + fl];
        FMAQ16(g0, s0);
    }
    if (e < e1) {                             // masked tail group (1-3 edges)
        int   i0 = e + q;
        bool  ok = i0 < e1;
        int   c0 = cols[ok ? i0 : e];
        float v0 = ok ? vals[i0] : 0.f;
        float s0 = v0 * scales[c0];
        uint4 g0 = sup16[(size_t)c0 * 16 + fl];
        FMAQ16(g0, s0);
    }

    // reduce across the 4 quarters (features are per-fl, common to quarters)
    #pragma unroll
    for (int j = 0; j < 16; ++j) {
        acc[j] += __shfl_xor(acc[j], 16);
        acc[j] += __shfl_xor(acc[j], 32);
    }
    S += __shfl_xor(S, 16);
    S += __shfl_xor(S, 32);

    // offset-binary correction: true dequant = (b - 128) * scale
    S *= 128.f;

    // epilogue: lane (q,fl) writes features fl*16 + q*4 .. +3
    const float4 b4 = ((const float4*)bias)[fl * 4 + q];
    f32x4 o;
    o.x = fminf(fmaxf(clampf(acc[q * 4 + 0] - S) + b4.x, 0.f), CLAMP_V);
    o.y = fminf(fmaxf(clampf(acc[q * 4 + 1] - S) + b4.y, 0.f), CLAMP_V);
    o.z = fminf(fmaxf(clampf(acc[q * 4 + 2] - S) + b4.z, 0.f), CLAMP_V);
    o.w = fminf(fmaxf(clampf(acc[q * 4 + 3] - S) + b4.w, 0.f), CLAMP_V);
    __builtin_nontemporal_store(o, (f32x4*)(out + (size_t)row * OUT_F + fl * 16 + q * 4));
}

// ---------------------------------------------------------------------------
extern "C" void kernel_launch(void* const* d_in, const int* in_sizes, int n_in,
                              void* d_out, int out_size, void* d_ws, size_t ws_size,
                              hipStream_t stream) {
    const float* x        = (const float*)d_in[0];
    const int*   adj_rows = (const int*)d_in[1];
    const int*   adj_cols = (const int*)d_in[2];
    const float* adj_vals = (const float*)d_in[3];
    const float* weight   = (const float*)d_in[4];
    const float* bias     = (const float*)d_in[5];
    float*       out      = (float*)d_out;

    // ws: sup8 25.6MB | scales 400KB | row_ptr 400KB | wt 128KB  (~26.5 MB)
    char* ws = (char*)d_ws;
    unsigned*       sup8    = (unsigned*)ws;                        // 25,600,000
    float*          scales  = (float*)(ws + 25600000);              //    400,000
    int*            row_ptr = (int*)(ws + 26000000);                //    400,004
    unsigned short* wt      = (unsigned short*)(ws + 26400064);     //    131,072

    const int rp_blocks = (N_NODES + 1 + 255) / 256;                // 392
    prep<<<256 + rp_blocks, 256, 0, stream>>>(weight, wt, adj_rows, row_ptr);
    gemm_mfma<<<(N_NODES + 63) / 64, 256, 0, stream>>>(x, wt, sup8, scales);
    spmm_out<<<(N_NODES + 3) / 4, 256, 0, stream>>>(sup8, scales, row_ptr,
                                                    adj_cols, adj_vals, bias, out);
}

// Round 12
// 174.344 us; speedup vs baseline: 1.1096x; 1.1096x over previous
//
#include <hip/hip_runtime.h>

#define N_NODES 100000
#define N_EDGES 3200000
#define IN_F    256
#define OUT_F   256
#define CLAMP_V 10.0f

typedef __attribute__((ext_vector_type(8))) short bf16x8;
typedef __attribute__((ext_vector_type(4))) float f32x4;

__device__ __forceinline__ float clampf(float v) {
    return fminf(fmaxf(v, -CLAMP_V), CLAMP_V);
}
// RNE float -> bf16 (inputs clamped/finite)
__device__ __forceinline__ unsigned f2bf(float f) {
    unsigned u = __float_as_uint(f);
    u += 0x7fffu + ((u >> 16) & 1u);
    return u >> 16;
}
// packed 2x f32 -> 2x bf16 in one u32
__device__ __forceinline__ unsigned cvt_pk_bf16(float lo, float hi) {
    unsigned r;
    asm("v_cvt_pk_bf16_f32 %0, %1, %2" : "=v"(r) : "v"(lo), "v"(hi));
    return r;
}
__device__ __forceinline__ float bflo(unsigned w) { return __uint_as_float(w << 16); }
__device__ __forceinline__ float bfhi(unsigned w) { return __uint_as_float(w & 0xffff0000u); }

// ---------------------------------------------------------------------------
// Kernel 0 (merged): blocks 0..255 convert W -> bf16 k-major
//   element (k,n) at ushort idx (k>>3)*2048 + n*8 + (k&7);
// blocks 256.. build CSR row_ptr from sorted adj_rows (binary search).
// ---------------------------------------------------------------------------
__global__ __launch_bounds__(256) void prep(
    const float* __restrict__ w, unsigned short* __restrict__ wt,
    const int* __restrict__ rows, int* __restrict__ row_ptr) {
    const int bid = blockIdx.x;
    if (bid < 256) {
        int i = bid * 256 + threadIdx.x;   // 65536
        int k = i & 255, n = i >> 8;
        float v = w[(size_t)k * OUT_F + n];
        int dst = ((k >> 3) << 11) + (n << 3) + (k & 7);
        wt[dst] = (unsigned short)f2bf(v);
    } else {
        int r = (bid - 256) * 256 + threadIdx.x;
        if (r > N_NODES) return;
        int lo = 0, hi = N_EDGES;
        while (lo < hi) {
            int mid = (lo + hi) >> 1;
            if (rows[mid] < r) lo = mid + 1; else hi = mid;
        }
        row_ptr[r] = lo;
    }
}

// ---------------------------------------------------------------------------
// Kernel 1: fused GEMM + int8 quantization, LDS-staged x streaming.
// (R10 version — delivered its prediction)
// ---------------------------------------------------------------------------
__global__ __launch_bounds__(256) void gemm_mfma(
    const float* __restrict__ x, const unsigned short* __restrict__ wt,
    unsigned* __restrict__ sup8, float* __restrict__ scales) {
    __shared__ char lds[32768];     // 2 x 16 KB staging; reused by epilogue

    const int t    = threadIdx.x;
    const int lane = t & 63;
    const int wc   = t >> 6;        // wave id = col slice 0..3
    const int l15  = lane & 15;
    const int l4   = lane >> 4;     // 0..3
    const int blockRow = blockIdx.x * 64;

    const int srow = t >> 2;        // 0..63
    const int sqt  = t & 3;         // 64B quarter of the 256B row-step slice
    int sgrow = blockRow + srow; if (sgrow >= N_NODES) sgrow = N_NODES - 1;
    const float* sbase = x + (size_t)sgrow * IN_F + sqt * 16;
    int woff[4];
    #pragma unroll
    for (int j = 0; j < 4; ++j) {
        int chunk = sqt * 4 + j;
        woff[j] = srow * 256 + ((chunk ^ (srow & 15)) << 4);
    }

    f32x4 st[4];
    #pragma unroll
    for (int j = 0; j < 4; ++j)
        st[j] = *(const f32x4*)(sbase + j * 4);      // K-step 0

    f32x4 acc[4][4];
    #pragma unroll
    for (int m = 0; m < 4; ++m)
        #pragma unroll
        for (int n = 0; n < 4; ++n)
            acc[m][n] = (f32x4)0.f;

    #pragma unroll
    for (int s = 0; s < 4; ++s) {
        char* buf = lds + (s & 1) * 16384;
        #pragma unroll
        for (int j = 0; j < 4; ++j)
            *(f32x4*)(buf + woff[j]) = st[j];
        if (s < 3) {                                  // prefetch next K-step
            const float* nb = sbase + (s + 1) * 64;
            #pragma unroll
            for (int j = 0; j < 4; ++j)
                st[j] = *(const f32x4*)(nb + j * 4);
        }
        __syncthreads();

        #pragma unroll
        for (int kk = 0; kk < 2; ++kk) {
            bf16x8 a[4], b[4];
            #pragma unroll
            for (int m = 0; m < 4; ++m) {
                const int row = m * 16 + l15;
                const int c0 = (kk * 8 + l4 * 2 + 0) ^ l15;
                const int c1 = (kk * 8 + l4 * 2 + 1) ^ l15;
                f32x4 u0 = *(const f32x4*)(buf + row * 256 + (c0 << 4));
                f32x4 u1 = *(const f32x4*)(buf + row * 256 + (c1 << 4));
                union { unsigned u[4]; bf16x8 v; } pk;
                pk.u[0] = cvt_pk_bf16(clampf(u0[0]), clampf(u0[1]));
                pk.u[1] = cvt_pk_bf16(clampf(u0[2]), clampf(u0[3]));
                pk.u[2] = cvt_pk_bf16(clampf(u1[0]), clampf(u1[1]));
                pk.u[3] = cvt_pk_bf16(clampf(u1[2]), clampf(u1[3]));
                a[m] = pk.v;
            }
            const int kg = s * 8 + kk * 4 + l4;       // global k>>3
            #pragma unroll
            for (int n = 0; n < 4; ++n)
                b[n] = *(const bf16x8*)(wt + (kg << 11) + ((wc * 64 + n * 16 + l15) << 3));
            #pragma unroll
            for (int m = 0; m < 4; ++m)
                #pragma unroll
                for (int n = 0; n < 4; ++n)
                    acc[m][n] = __builtin_amdgcn_mfma_f32_16x16x32_bf16(
                        a[m], b[n], acc[m][n], 0, 0, 0);
        }
    }
    __syncthreads();

    // ---- epilogue A: acc -> LDS bf16 (chunk-swizzled), 64 x 512 B ----
    {
        char* sl = lds;
        #pragma unroll
        for (int m = 0; m < 4; ++m) {
            #pragma unroll
            for (int n = 0; n < 4; ++n) {
                int col2 = (wc * 64 + n * 16 + l15) * 2;
                #pragma unroll
                for (int r = 0; r < 4; ++r) {
                    int row = m * 16 + l4 * 4 + r;
                    int off = row * 512 + (col2 ^ (((row >> 2) & 3) << 4));
                    *(unsigned short*)(sl + off) = (unsigned short)f2bf(clampf(acc[m][n][r]));
                }
            }
        }
    }
    __syncthreads();

    // ---- epilogue B: rowmax + quantize + int8 store ----
    {
        const uint4* sl4 = (const uint4*)lds;
        const int row = t >> 2;         // 0..63
        const int qt  = t & 3;          // quarter of the row (64 feats)
        const int swz = (row >> 2) & 3;

        uint4 c[8];
        float mx = 0.f;
        #pragma unroll
        for (int j = 0; j < 8; ++j) {
            c[j] = sl4[row * 32 + ((qt * 8 + j) ^ swz)];
            const unsigned* cu = (const unsigned*)&c[j];
            #pragma unroll
            for (int q = 0; q < 4; ++q)
                mx = fmaxf(mx, fmaxf(fabsf(bflo(cu[q])), fabsf(bfhi(cu[q]))));
        }
        mx = fmaxf(mx, __shfl_xor(mx, 1));
        mx = fmaxf(mx, __shfl_xor(mx, 2));   // rowmax in all 4 quarter-threads

        const float inv = 127.f / fmaxf(mx, 1e-30f);
        const int grow = blockRow + row;
        if (grow < N_NODES) {
            unsigned p[16];
            #pragma unroll
            for (int j = 0; j < 8; ++j) {
                const unsigned* cu = (const unsigned*)&c[j];
                #pragma unroll
                for (int q = 0; q < 2; ++q) {
                    unsigned b0 = (unsigned)(int)rintf(bflo(cu[q*2+0]) * inv) + 128u;
                    unsigned b1 = (unsigned)(int)rintf(bfhi(cu[q*2+0]) * inv) + 128u;
                    unsigned b2 = (unsigned)(int)rintf(bflo(cu[q*2+1]) * inv) + 128u;
                    unsigned b3 = (unsigned)(int)rintf(bfhi(cu[q*2+1]) * inv) + 128u;
                    p[j*2+q] = b0 | (b1 << 8) | (b2 << 16) | (b3 << 24);
                }
            }
            uint4* dst = (uint4*)(sup8 + (size_t)grow * 64 + qt * 16);
            #pragma unroll
            for (int j = 0; j < 4; ++j)
                dst[j] = *(const uint4*)&p[j * 4];
            if (qt == 0) scales[grow] = mx * (1.f / 127.f);
        }
    }
}

// ---------------------------------------------------------------------------
// Kernel 2: out[r] = clip(relu(clip(sum val*support[c]) + bias)).
// R10 shape (best measured): one wave per row; lanes 0-31 even edges,
// 32-63 odd edges; 8 B (8 int8 feats) per lane per edge; 8-edge main loop.
// Dequant folded: acc += (val*scale)*ubyte, single -128*S correction.
// ---------------------------------------------------------------------------
#define FMAQ(g, vs)                                                       \
    S += (vs);                                                            \
    acc[0] += (vs) * (float)((g).x & 0xffu);                              \
    acc[1] += (vs) * (float)(((g).x >> 8) & 0xffu);                       \
    acc[2] += (vs) * (float)(((g).x >> 16) & 0xffu);                      \
    acc[3] += (vs) * (float)((g).x >> 24);                                \
    acc[4] += (vs) * (float)((g).y & 0xffu);                              \
    acc[5] += (vs) * (float)(((g).y >> 8) & 0xffu);                       \
    acc[6] += (vs) * (float)(((g).y >> 16) & 0xffu);                      \
    acc[7] += (vs) * (float)((g).y >> 24);

__global__ __launch_bounds__(256) void spmm_out(
    const unsigned* __restrict__ sup8, const float* __restrict__ scales,
    const int* __restrict__ row_ptr, const int* __restrict__ cols,
    const float* __restrict__ vals, const float* __restrict__ bias,
    float* __restrict__ out) {
    const int wid  = threadIdx.x >> 6;
    const int lane = threadIdx.x & 63;
    const int row  = blockIdx.x * 4 + wid;
    if (row >= N_NODES) return;

    const int e0   = row_ptr[row];
    const int e1   = row_ptr[row + 1];
    const int half = lane >> 5;       // 0: even edges, 1: odd edges
    const int c32  = lane & 31;       // 8B chunk within node row

    const uint2* sup2 = (const uint2*)sup8;
    float acc[8] = {0.f,0.f,0.f,0.f,0.f,0.f,0.f,0.f};
    float S = 0.f;

    int e = e0;
    for (; e + 8 <= e1; e += 8) {
        int   ea = e + half, eb = ea + 2, ec = ea + 4, ed = ea + 6;
        int   ca = cols[ea], cb = cols[eb], cc = cols[ec], cd = cols[ed];
        float va = vals[ea], vb = vals[eb], vc = vals[ec], vd = vals[ed];
        float vsa = va * scales[ca], vsb = vb * scales[cb];
        float vsc = vc * scales[cc], vsd = vd * scales[cd];
        uint2 ga = sup2[(size_t)ca * 32 + c32];
        uint2 gb = sup2[(size_t)cb * 32 + c32];
        uint2 gc = sup2[(size_t)cc * 32 + c32];
        uint2 gd = sup2[(size_t)cd * 32 + c32];
        FMAQ(ga, vsa); FMAQ(gb, vsb); FMAQ(gc, vsc); FMAQ(gd, vsd);
    }
    for (; e + 4 <= e1; e += 4) {
        int   ea = e + half, eb = ea + 2;
        int   ca = cols[ea], cb = cols[eb];
        float va = vals[ea], vb = vals[eb];
        float vsa = va * scales[ca], vsb = vb * scales[cb];
        uint2 ga = sup2[(size_t)ca * 32 + c32];
        uint2 gb = sup2[(size_t)cb * 32 + c32];
        FMAQ(ga, vsa); FMAQ(gb, vsb);
    }
    for (; e < e1; e += 2) {
        int   ea = e + half;
        bool  ok = ea < e1;
        int   ca = cols[ok ? ea : e];
        float va = ok ? vals[ea] : 0.f;
        float vsa = va * scales[ca];
        uint2 ga = sup2[(size_t)ca * 32 + c32];
        FMAQ(ga, vsa);
    }

    // offset-binary correction: true dequant = (b - 128) * scale
    S *= 128.f;
    #pragma unroll
    for (int j = 0; j < 8; ++j)
        acc[j] -= S;

    #pragma unroll
    for (int j = 0; j < 8; ++j)
        acc[j] += __shfl_xor(acc[j], 32);

    const float4 b4 = ((const float4*)bias)[c32 * 2 + half];
    f32x4 o;
    o.x = fminf(fmaxf(clampf(acc[half * 4 + 0]) + b4.x, 0.f), CLAMP_V);
    o.y = fminf(fmaxf(clampf(acc[half * 4 + 1]) + b4.y, 0.f), CLAMP_V);
    o.z = fminf(fmaxf(clampf(acc[half * 4 + 2]) + b4.z, 0.f), CLAMP_V);
    o.w = fminf(fmaxf(clampf(acc[half * 4 + 3]) + b4.w, 0.f), CLAMP_V);
    __builtin_nontemporal_store(o, (f32x4*)(out + (size_t)row * OUT_F + c32 * 8 + half * 4));
}

// ---------------------------------------------------------------------------
extern "C" void kernel_launch(void* const* d_in, const int* in_sizes, int n_in,
                              void* d_out, int out_size, void* d_ws, size_t ws_size,
                              hipStream_t stream) {
    const float* x        = (const float*)d_in[0];
    const int*   adj_rows = (const int*)d_in[1];
    const int*   adj_cols = (const int*)d_in[2];
    const float* adj_vals = (const float*)d_in[3];
    const float* weight   = (const float*)d_in[4];
    const float* bias     = (const float*)d_in[5];
    float*       out      = (float*)d_out;

    // ws: sup8 25.6MB | scales 400KB | row_ptr 400KB | wt 128KB  (~26.5 MB)
    char* ws = (char*)d_ws;
    unsigned*       sup8    = (unsigned*)ws;                        // 25,600,000
    float*          scales  = (float*)(ws + 25600000);              //    400,000
    int*            row_ptr = (int*)(ws + 26000000);                //    400,004
    unsigned short* wt      = (unsigned short*)(ws + 26400064);     //    131,072

    const int rp_blocks = (N_NODES + 1 + 255) / 256;                // 392
    prep<<<256 + rp_blocks, 256, 0, stream>>>(weight, wt, adj_rows, row_ptr);
    gemm_mfma<<<(N_NODES + 63) / 64, 256, 0, stream>>>(x, wt, sup8, scales);
    spmm_out<<<(N_NODES + 3) / 4, 256, 0, stream>>>(sup8, scales, row_ptr,
                                                    adj_cols, adj_vals, bias, out);
}